// Round 8
// baseline (13672.124 us; speedup 1.0000x reference)
//
#include <hip/hip_runtime.h>

// LSTM T=4096, IN=32, H=512, OUT=32, 3 layers + projection.
// R8 = R7 sync protocol + 4x cheaper LDS dot.
//   R7 post-mortem: dot was 256 ds_read_b128 broadcast wave-instrs/step/WG;
//   LDS return path charges 1KiB per wave64 b128 regardless of broadcast ->
//   ~3100 cyc/step of LDS pipe = the dominant term (not sync).
//   Fix: lane covers 4 rows x 16 k (was 1 row x 64 k): same 64 MACs, same
//   64 weight regs, but 64 b128 instrs/step (4x less LDS).
// Layout: 32 WGs/layer x 1024 thr. wv=tid>>6, sub=lane>>4, cl=lane&15.
//   k-chunk = wv*4+sub (64 chunks). Layers 1/2: chunk<32 -> prev-h/Wih,
//   else own-h/Whh, 16 k each. Layer 0: 8 k of own-h/Whh; chunks 0..7 also
//   take 4 x-k of Wih. Lane's 4 rows = gates i,f,g,o of column g*16+cl.
//   Reduce: shfl_xor(16,32) -> lanes 0-15 write float4 part[wv][cl][4];
//   wave0: 16 strided b32 sums, gates, ONE 128B coalesced publish (R6/R7).
// Invariants (hard-won): no cache-wide fences (R2); no runtime indexing of
//   private arrays (R4); <=64+16 weight floats/lane (R5/R6); publish = one
//   wave, one full line (R6).

#define T_SEQ 4096
#define HDIM  512
#define NWG_L 32
#define NTH   1024

typedef unsigned long long u64;

__device__ __forceinline__ u64 cohLoad(const u64* p) {
    return __hip_atomic_load(p, __ATOMIC_RELAXED, __HIP_MEMORY_SCOPE_AGENT);
}
__device__ __forceinline__ void cohStore(u64* p, u64 v) {
    __hip_atomic_store(p, v, __ATOMIC_RELAXED, __HIP_MEMORY_SCOPE_AGENT);
}
__device__ __forceinline__ float fsigmoid(float x) {
    return __builtin_amdgcn_rcpf(1.f + __expf(-x));
}
__device__ __forceinline__ float ftanh(float x) {
    float e = __expf(2.f * fabsf(x));           // +inf ok -> t = 1
    float t = 1.f - 2.f * __builtin_amdgcn_rcpf(e + 1.f);
    return copysignf(t, x);
}

// ---------------------------------------------------------------------------
// Tiled fp32 GEMM (final projection): C[M][N] = A[M][K] * B[N][K]^T + bias[n]
// ---------------------------------------------------------------------------
template <int BM, int BN, int BK>
__global__ __launch_bounds__(256)
void gemm_abt(const float* __restrict__ A, const float* __restrict__ B,
              const float* __restrict__ bias1,
              float* __restrict__ C, int M, int N, int K) {
    constexpr int NTX = BN / 4;
    constexpr int NTY = 256 / NTX;
    constexpr int TM  = BM / NTY;
    __shared__ float As[BM][BK + 1];
    __shared__ float Bs[BN][BK + 1];

    const int tid = threadIdx.x;
    const int tx = tid % NTX;
    const int ty = tid / NTX;
    const int m0 = blockIdx.y * BM;
    const int n0 = blockIdx.x * BN;

    float acc[TM][4];
    #pragma unroll
    for (int i = 0; i < TM; ++i)
        #pragma unroll
        for (int j = 0; j < 4; ++j) acc[i][j] = 0.f;

    for (int k0 = 0; k0 < K; k0 += BK) {
        constexpr int AV = BM * BK / 4;
        #pragma unroll
        for (int i = tid; i < AV; i += 256) {
            int r = i / (BK / 4), c4 = i % (BK / 4);
            float4 v = *(const float4*)(A + (size_t)(m0 + r) * K + k0 + c4 * 4);
            As[r][c4 * 4 + 0] = v.x; As[r][c4 * 4 + 1] = v.y;
            As[r][c4 * 4 + 2] = v.z; As[r][c4 * 4 + 3] = v.w;
        }
        constexpr int BV = BN * BK / 4;
        #pragma unroll
        for (int i = tid; i < BV; i += 256) {
            int r = i / (BK / 4), c4 = i % (BK / 4);
            float4 v = *(const float4*)(B + (size_t)(n0 + r) * K + k0 + c4 * 4);
            Bs[r][c4 * 4 + 0] = v.x; Bs[r][c4 * 4 + 1] = v.y;
            Bs[r][c4 * 4 + 2] = v.z; Bs[r][c4 * 4 + 3] = v.w;
        }
        __syncthreads();
        #pragma unroll
        for (int kk = 0; kk < BK; ++kk) {
            float a[TM], b[4];
            #pragma unroll
            for (int i = 0; i < TM; ++i) a[i] = As[ty * TM + i][kk];
            #pragma unroll
            for (int j = 0; j < 4; ++j) b[j] = Bs[tx * 4 + j][kk];
            #pragma unroll
            for (int i = 0; i < TM; ++i)
                #pragma unroll
                for (int j = 0; j < 4; ++j) acc[i][j] += a[i] * b[j];
        }
        __syncthreads();
    }

    #pragma unroll
    for (int j = 0; j < 4; ++j) {
        float bv = bias1 ? bias1[n0 + tx * 4 + j] : 0.f;
        #pragma unroll
        for (int i = 0; i < TM; ++i) acc[i][j] += bv;
    }
    #pragma unroll
    for (int i = 0; i < TM; ++i) {
        int m = m0 + ty * TM + i;
        float4 v = make_float4(acc[i][0], acc[i][1], acc[i][2], acc[i][3]);
        *(float4*)(C + (size_t)m * N + n0 + tx * 4) = v;
    }
}

// ---------------------------------------------------------------------------
__global__ void unpack_h(const u64* __restrict__ hp, float* __restrict__ out,
                         int n) {
    int i = blockIdx.x * blockDim.x + threadIdx.x;
    if (i < n) out[i] = __uint_as_float((unsigned)hp[i]);
}

// ---------------------------------------------------------------------------
__global__ __launch_bounds__(NTH, 4)
void lstm_fused(const float* __restrict__ seq,
                const float* __restrict__ Wih1, const float* __restrict__ Whh1,
                const float* __restrict__ bih1, const float* __restrict__ bhh1,
                const float* __restrict__ Wih2, const float* __restrict__ Whh2,
                const float* __restrict__ bih2, const float* __restrict__ bhh2,
                const float* __restrict__ Wih3, const float* __restrict__ Whh3,
                const float* __restrict__ bih3, const float* __restrict__ bhh3,
                u64* __restrict__ hp) {
    // layers 1/2: h_in = [prev-h(512) | own-h(512)]
    // layer 0:    h_in = [own-h(512) | x(32)]
    __shared__ __align__(16) float h_in[2][1024 + 32];
    __shared__ __align__(16) float part[16 * 16 * 4];   // [wv][cl][gate]

    const int blk   = blockIdx.x;
    const int layer = blk >> 5;
    const int g     = blk & 31;
    const int tid   = threadIdx.x;
    const int wv    = tid >> 6;          // 0..15
    const int lane  = tid & 63;
    const int sub   = lane >> 4;         // 0..3 (k sub-chunk)
    const int cl    = lane & 15;         // column-local
    const int chunk = wv * 4 + sub;      // 0..63
    const int gate  = lane >> 4;         // wave-0 tail alias (gate = sub)
    const int col0  = g * 16 + cl;       // this lane's column

    const float* Wih = layer == 0 ? Wih1 : (layer == 1 ? Wih2 : Wih3);
    const float* Whh = layer == 0 ? Whh1 : (layer == 1 ? Whh2 : Whh3);
    const float* bih = layer == 0 ? bih1 : (layer == 1 ? bih2 : bih3);
    const float* bhh = layer == 0 ? bhh1 : (layer == 1 ? bhh2 : bhh3);

    // ---- weights: 4 rows (gates of col0) x 16 k (layers 1/2) or
    //      4 rows x 8 h-k (+ 4 x-k for chunks 0-7) into registers ----
    float wh[64];
    float wx[16];
    #pragma unroll
    for (int m = 0; m < 64; ++m) wh[m] = 0.f;
    #pragma unroll
    for (int m = 0; m < 16; ++m) wx[m] = 0.f;

    if (layer == 0) {
        const int k0 = chunk * 8;
        #pragma unroll
        for (int r = 0; r < 4; ++r) {
            const float* wp = Whh + (size_t)(r * HDIM + col0) * HDIM + k0;
            #pragma unroll
            for (int k4 = 0; k4 < 2; ++k4) {
                float4 v = ((const float4*)wp)[k4];
                wh[r*8 + 4*k4 + 0] = v.x; wh[r*8 + 4*k4 + 1] = v.y;
                wh[r*8 + 4*k4 + 2] = v.z; wh[r*8 + 4*k4 + 3] = v.w;
            }
        }
        if (chunk < 8) {
            #pragma unroll
            for (int r = 0; r < 4; ++r) {
                float4 v = *(const float4*)(Wih + (size_t)(r * HDIM + col0) * 32
                                            + chunk * 4);
                wx[r*4+0]=v.x; wx[r*4+1]=v.y; wx[r*4+2]=v.z; wx[r*4+3]=v.w;
            }
        }
    } else {
        const float* Wsrc = (chunk < 32) ? Wih : Whh;
        const int k0 = (chunk < 32 ? chunk : chunk - 32) * 16;
        #pragma unroll
        for (int r = 0; r < 4; ++r) {
            const float* wp = Wsrc + (size_t)(r * HDIM + col0) * HDIM + k0;
            #pragma unroll
            for (int k4 = 0; k4 < 4; ++k4) {
                float4 v = ((const float4*)wp)[k4];
                wh[r*16 + 4*k4 + 0] = v.x; wh[r*16 + 4*k4 + 1] = v.y;
                wh[r*16 + 4*k4 + 2] = v.z; wh[r*16 + 4*k4 + 3] = v.w;
            }
        }
    }
    #pragma unroll
    for (int m = 0; m < 64; ++m) asm volatile("" : "+v"(wh[m]));
    #pragma unroll
    for (int m = 0; m < 16; ++m) asm volatile("" : "+v"(wx[m]));

    // bias for wave-0 tail (lane = gate*16+cl owns row gate*512+col0)
    const float brow = bih[gate * HDIM + col0] + bhh[gate * HDIM + col0];

    u64*       hpOwn  = hp + (size_t)layer * T_SEQ * HDIM;
    const u64* hpPrev = hp + (size_t)(layer > 0 ? layer - 1 : 0) * T_SEQ * HDIM;

    float c = 0.f;   // cell state (wave 0, lanes 0..15)

    for (unsigned t = 0; t < T_SEQ; ++t) {
        const int pb = t & 1;
        // ---- stage: each thread polls exactly one element (tag = data) ----
        if (layer == 0) {
            if (tid < HDIM) {
                float hv = 0.f;
                if (t > 0) {
                    const u64* ph = hpOwn + (size_t)(t - 1) * HDIM + tid;
                    u64 v;
                    do { v = cohLoad(ph); } while ((unsigned)(v >> 32) != t);
                    hv = __uint_as_float((unsigned)v);
                }
                h_in[pb][tid] = hv;
            } else if (tid < HDIM + 32) {
                h_in[pb][tid] = seq[(size_t)t * 32 + (tid - HDIM)];
            }
        } else {
            if (tid < HDIM) {                    // prev-layer h[t], tag t+1
                const u64* px = hpPrev + (size_t)t * HDIM + tid;
                u64 v;
                do { v = cohLoad(px); } while ((unsigned)(v >> 32) != t + 1u);
                h_in[pb][tid] = __uint_as_float((unsigned)v);
            } else {                             // own h[t-1], tag t
                float hv = 0.f;
                if (t > 0) {
                    const u64* ph = hpOwn + (size_t)(t - 1) * HDIM + (tid - HDIM);
                    u64 v;
                    do { v = cohLoad(ph); } while ((unsigned)(v >> 32) != t);
                    hv = __uint_as_float((unsigned)v);
                }
                h_in[pb][tid] = hv;
            }
        }
        __syncthreads();

        // ---- dot: 4 rows x 16k (or 8k+4xk) per lane, const w indices ----
        float p0 = 0.f, p1 = 0.f, p2 = 0.f, p3 = 0.f;
        if (layer == 0) {
            const float4* hb = (const float4*)(h_in[pb]) + chunk * 2;
            #pragma unroll
            for (int k4 = 0; k4 < 2; ++k4) {
                float4 hv = hb[k4];
                p0 += wh[0*8+4*k4+0]*hv.x + wh[0*8+4*k4+1]*hv.y
                    + wh[0*8+4*k4+2]*hv.z + wh[0*8+4*k4+3]*hv.w;
                p1 += wh[1*8+4*k4+0]*hv.x + wh[1*8+4*k4+1]*hv.y
                    + wh[1*8+4*k4+2]*hv.z + wh[1*8+4*k4+3]*hv.w;
                p2 += wh[2*8+4*k4+0]*hv.x + wh[2*8+4*k4+1]*hv.y
                    + wh[2*8+4*k4+2]*hv.z + wh[2*8+4*k4+3]*hv.w;
                p3 += wh[3*8+4*k4+0]*hv.x + wh[3*8+4*k4+1]*hv.y
                    + wh[3*8+4*k4+2]*hv.z + wh[3*8+4*k4+3]*hv.w;
            }
            if (chunk < 8) {
                float4 xv = ((const float4*)(h_in[pb] + HDIM))[chunk];
                p0 += wx[0]*xv.x + wx[1]*xv.y + wx[2]*xv.z + wx[3]*xv.w;
                p1 += wx[4]*xv.x + wx[5]*xv.y + wx[6]*xv.z + wx[7]*xv.w;
                p2 += wx[8]*xv.x + wx[9]*xv.y + wx[10]*xv.z + wx[11]*xv.w;
                p3 += wx[12]*xv.x + wx[13]*xv.y + wx[14]*xv.z + wx[15]*xv.w;
            }
        } else {
            const float4* hb = (const float4*)(h_in[pb]) + chunk * 4;
            #pragma unroll
            for (int k4 = 0; k4 < 4; ++k4) {
                float4 hv = hb[k4];
                p0 += wh[0*16+4*k4+0]*hv.x + wh[0*16+4*k4+1]*hv.y
                    + wh[0*16+4*k4+2]*hv.z + wh[0*16+4*k4+3]*hv.w;
                p1 += wh[1*16+4*k4+0]*hv.x + wh[1*16+4*k4+1]*hv.y
                    + wh[1*16+4*k4+2]*hv.z + wh[1*16+4*k4+3]*hv.w;
                p2 += wh[2*16+4*k4+0]*hv.x + wh[2*16+4*k4+1]*hv.y
                    + wh[2*16+4*k4+2]*hv.z + wh[2*16+4*k4+3]*hv.w;
                p3 += wh[3*16+4*k4+0]*hv.x + wh[3*16+4*k4+1]*hv.y
                    + wh[3*16+4*k4+2]*hv.z + wh[3*16+4*k4+3]*hv.w;
            }
        }

        // ---- in-wave reduce over the 4 sub-chunks (xor 16, 32) ----
        p0 += __shfl_xor(p0, 16, 64); p1 += __shfl_xor(p1, 16, 64);
        p2 += __shfl_xor(p2, 16, 64); p3 += __shfl_xor(p3, 16, 64);
        p0 += __shfl_xor(p0, 32, 64); p1 += __shfl_xor(p1, 32, 64);
        p2 += __shfl_xor(p2, 32, 64); p3 += __shfl_xor(p3, 32, 64);
        if (lane < 16) {
            float4 st = make_float4(p0, p1, p2, p3);
            ((float4*)part)[wv * 16 + lane] = st;   // part[wv][cl][0..3]
        }
        __syncthreads();

        // ---- wave 0: cross-wave sum, gates, ONE coalesced 128B publish ----
        if (wv == 0) {
            float tot = brow;
            #pragma unroll
            for (int wvv = 0; wvv < 16; ++wvv)
                tot += part[wvv * 64 + cl * 4 + gate];
            float ai = __shfl(tot, cl +  0, 64);
            float af = __shfl(tot, cl + 16, 64);
            float ag = __shfl(tot, cl + 32, 64);
            float ao = __shfl(tot, cl + 48, 64);
            if (lane < 16) {
                float iv = fsigmoid(ai);
                float fv = fsigmoid(af);
                float gv = ftanh(ag);
                float ov = fsigmoid(ao);
                c = fv * c + iv * gv;
                float h = ov * ftanh(c);
                u64 pkt = (u64)__float_as_uint(h) | ((u64)(t + 1u) << 32);
                cohStore(hpOwn + (size_t)t * HDIM + g * 16 + lane, pkt);
            }
        }
        // next staging writes the other h_in buffer; part(t+1) writes happen
        // only after B1(t+1), which wave 0 joins after its tail -> safe.
    }
}

// ---------------------------------------------------------------------------
extern "C" void kernel_launch(void* const* d_in, const int* in_sizes, int n_in,
                              void* d_out, int out_size, void* d_ws, size_t ws_size,
                              hipStream_t stream) {
    const float* seq   = (const float*)d_in[0];
    const float* W_ih1 = (const float*)d_in[1];
    const float* W_hh1 = (const float*)d_in[2];
    const float* b_ih1 = (const float*)d_in[3];
    const float* b_hh1 = (const float*)d_in[4];
    const float* W_ih2 = (const float*)d_in[5];
    const float* W_hh2 = (const float*)d_in[6];
    const float* b_ih2 = (const float*)d_in[7];
    const float* b_hh2 = (const float*)d_in[8];
    const float* W_ih3 = (const float*)d_in[9];
    const float* W_hh3 = (const float*)d_in[10];
    const float* b_ih3 = (const float*)d_in[11];
    const float* b_hh3 = (const float*)d_in[12];
    const float* W_out = (const float*)d_in[13];
    const float* b_out = (const float*)d_in[14];
    float* out = (float*)d_out;

    // Workspace: hp[3][T][512] packed u64 (50.3MB); hs2 floats reuse the
    // dead layer-0 packed region after the recurrence.
    u64*   hp   = (u64*)d_ws;
    float* hs2f = (float*)d_ws;
    const u64* hp2 = hp + (size_t)2 * T_SEQ * HDIM;

    hipMemsetAsync(hp, 0, (size_t)3 * T_SEQ * HDIM * sizeof(u64), stream);

    lstm_fused<<<3 * NWG_L, NTH, 0, stream>>>(
        seq, W_ih1, W_hh1, b_ih1, b_hh1, W_ih2, W_hh2, b_ih2, b_hh2,
        W_ih3, W_hh3, b_ih3, b_hh3, hp);

    const int n = T_SEQ * HDIM;
    unpack_h<<<(n + 255) / 256, 256, 0, stream>>>(hp2, hs2f, n);

    gemm_abt<64, 32, 32><<<dim3(1, T_SEQ / 64), 256, 0, stream>>>(
        hs2f, W_out, b_out, out, T_SEQ, 32, HDIM);
}